// Round 7
// baseline (508.947 us; speedup 1.0000x reference)
//
#include <hip/hip_runtime.h>
#include <hip/hip_bf16.h>

typedef __hip_bfloat16 bf16;
typedef __attribute__((ext_vector_type(8))) short short8;
typedef __attribute__((ext_vector_type(4))) float f32x4;

#define DEV static __device__ __forceinline__

DEV float b2f(bf16 v) { return __bfloat162float(v); }
DEV bf16 f2b(float v) { return __float2bfloat16(v); }
DEV unsigned short f2bu(float v) { return __builtin_bit_cast(unsigned short, __float2bfloat16(v)); }
DEV float u2f(unsigned short u) { return __uint_as_float(((unsigned int)u) << 16); }
DEV float gelu(float x) { return 0.5f * x * (1.0f + erff(x * 0.70710678118654752f)); }

// Problem constants
#define BB 64
#define NT 139     // 1 + T + G1
#define DD 384
#define TT 10
#define HH 6
#define GG 138     // G1 + T
#define M1 8896    // BB*NT
#define MG 8832    // BB*GG
#define NGRP 2048  // BB*S
#define SCALE 0.125f

// Workspace byte offsets
#define XC_OFF   0UL          // f32 8896x384 residual stream, live whole call
#define VIS_OFF  13664256UL   // f32 2048x384
#define XNB_OFF  16809984UL   // bf16 8896x384: LN out; attn1 o
#define XFN_OFF  23642112UL   // f32 8896x384: fc2 out; later x_prop
#define BIG1_OFF 37875712UL   // bf16 8896x1152: qkv / qkv1
#define BIG2_OFF 58372096UL   // bf16 8896x1536 fc1h / bf16 32768x384 o1
#define ATT_OFF  XNB_OFF      // bf16 32768x384 proj1 out (overlays dead regions)
#define WB_OFF   85700608UL   // bf16 2359296: pre-converted weights

#define WB_QKV   0
#define WB_PROJ  442368
#define WB_FC1   589824
#define WB_FC2   1179648
#define WB_QKV1  1769472
#define WB_PROJ1 2211840
#define WB_TOTAL 2359296

#define OUT_X 3170304  // 64*129*384

DEV float4 ld4(const float* p) { return *(const float4*)p; }
DEV void stc(float* p, float v) { *p = v; }
DEV void stc(bf16* p, float v) { *p = f2b(v); }

// ---------- weights f32 -> bf16 ----------
__global__ __launch_bounds__(256) void k_wconv(const float* __restrict__ w0, const float* __restrict__ w1,
                                               const float* __restrict__ w2, const float* __restrict__ w3,
                                               const float* __restrict__ w4, const float* __restrict__ w5,
                                               bf16* __restrict__ dst) {
    int i4 = (blockIdx.x * 256 + threadIdx.x) * 4;
    if (i4 >= WB_TOTAL) return;
    const float* s; int off;
    if (i4 < WB_PROJ)       { s = w0; off = WB_QKV; }
    else if (i4 < WB_FC1)   { s = w1; off = WB_PROJ; }
    else if (i4 < WB_FC2)   { s = w2; off = WB_FC1; }
    else if (i4 < WB_QKV1)  { s = w3; off = WB_FC2; }
    else if (i4 < WB_PROJ1) { s = w4; off = WB_QKV1; }
    else                    { s = w5; off = WB_PROJ1; }
    float4 v = *(const float4*)(s + (i4 - off));
    ushort4 u;
    u.x = f2bu(v.x); u.y = f2bu(v.y); u.z = f2bu(v.z); u.w = f2bu(v.w);
    *(ushort4*)((unsigned short*)dst + i4) = u;
}

// ---------- fused concat + LN1: gather row from x/prompt, write xc f32 + ln bf16 ----------
__global__ __launch_bounds__(128) void k_ln1(const float* __restrict__ x, const float* __restrict__ pe,
                                             const float* __restrict__ g, const float* __restrict__ bta,
                                             float* __restrict__ xc, bf16* __restrict__ dst) {
    int r = blockIdx.x;
    int b = r / NT, n = r % NT;
    const float* p;
    if (n == 0)       p = x + (size_t)(b * 129) * DD;
    else if (n <= TT) p = pe + (size_t)(n - 1) * DD;
    else              p = x + (size_t)(b * 129 + n - TT) * DD;
    int t = threadIdx.x;
    float v0 = p[t], v1 = p[t + 128], v2 = p[t + 256];
    float* xq = xc + (size_t)r * DD;
    xq[t] = v0; xq[t + 128] = v1; xq[t + 256] = v2;
    __shared__ float red[4];
    float s = v0 + v1 + v2;
    for (int off = 32; off; off >>= 1) s += __shfl_down(s, off, 64);
    if ((t & 63) == 0) red[t >> 6] = s;
    __syncthreads();
    float mean = (red[0] + red[1]) * (1.0f / 384.0f);
    float d0 = v0 - mean, d1 = v1 - mean, d2 = v2 - mean;
    float s2 = d0 * d0 + d1 * d1 + d2 * d2;
    for (int off = 32; off; off >>= 1) s2 += __shfl_down(s2, off, 64);
    if ((t & 63) == 0) red[2 + (t >> 6)] = s2;
    __syncthreads();
    float rstd = rsqrtf((red[2] + red[3]) * (1.0f / 384.0f) + 1e-5f);
    bf16* q = dst + (size_t)r * DD;
    q[t]       = f2b(d0 * rstd * g[t]       + bta[t]);
    q[t + 128] = f2b(d1 * rstd * g[t + 128] + bta[t + 128]);
    q[t + 256] = f2b(d2 * rstd * g[t + 256] + bta[t + 256]);
}

// ---------- layernorm f32 -> bf16 (mode 1: gather row (r/138)*139+1+(r%138)) ----------
__global__ __launch_bounds__(128) void k_layernorm(const float* __restrict__ src, bf16* __restrict__ dst,
                                                   const float* __restrict__ g, const float* __restrict__ bta,
                                                   int mode) {
    int r = blockIdx.x;
    int srow = r;
    if (mode) srow = (r / GG) * NT + 1 + (r % GG);
    const float* p = src + (size_t)srow * DD;
    int t = threadIdx.x;
    float v0 = p[t], v1 = p[t + 128], v2 = p[t + 256];
    __shared__ float red[4];
    float s = v0 + v1 + v2;
    for (int off = 32; off; off >>= 1) s += __shfl_down(s, off, 64);
    if ((t & 63) == 0) red[t >> 6] = s;
    __syncthreads();
    float mean = (red[0] + red[1]) * (1.0f / 384.0f);
    float d0 = v0 - mean, d1 = v1 - mean, d2 = v2 - mean;
    float s2 = d0 * d0 + d1 * d1 + d2 * d2;
    for (int off = 32; off; off >>= 1) s2 += __shfl_down(s2, off, 64);
    if ((t & 63) == 0) red[2 + (t >> 6)] = s2;
    __syncthreads();
    float rstd = rsqrtf((red[2] + red[3]) * (1.0f / 384.0f) + 1e-5f);
    bf16* q = dst + (size_t)r * DD;
    q[t]       = f2b(d0 * rstd * g[t]       + bta[t]);
    q[t + 128] = f2b(d1 * rstd * g[t + 128] + bta[t + 128]);
    q[t + 256] = f2b(d2 * rstd * g[t + 256] + bta[t + 256]);
}

// ---------- MFMA GEMM (BM=64 BN=64 BK=64, reg-prefetch pipeline) ----------
template <typename TC>
__global__ __launch_bounds__(256) void mf_gemm(const bf16* __restrict__ A, const bf16* __restrict__ W,
                                               const float* __restrict__ bias, const float* __restrict__ res,
                                               TC* __restrict__ C, int M, int N, int K, int act) {
    __shared__ bf16 As[64][72];
    __shared__ bf16 Ws[64][72];
    int t = threadIdx.x;
    int m0 = blockIdx.y * 64, n0 = blockIdx.x * 64;
    int lane = t & 63, wv = t >> 6;
    int wm = (wv >> 1) * 32, wn = (wv & 1) * 32;
    int fr = lane & 15, fq = lane >> 4;
    int sr = t >> 2, sc = (t & 3) * 16;
    const bf16* pa = A + (size_t)(m0 + sr) * K + sc;
    const bf16* pw = W + (size_t)(n0 + sr) * K + sc;
    uint4 ra0 = *(const uint4*)pa;
    uint4 ra1 = *(const uint4*)(pa + 8);
    uint4 rw0 = *(const uint4*)pw;
    uint4 rw1 = *(const uint4*)(pw + 8);
    f32x4 acc[2][2] = {};
    int k0 = 0;
    for (;;) {
        *(uint4*)&As[sr][sc] = ra0; *(uint4*)&As[sr][sc + 8] = ra1;
        *(uint4*)&Ws[sr][sc] = rw0; *(uint4*)&Ws[sr][sc + 8] = rw1;
        __syncthreads();
        k0 += 64;
        bool more = (k0 < K);
        if (more) {
            ra0 = *(const uint4*)(pa + k0); ra1 = *(const uint4*)(pa + k0 + 8);
            rw0 = *(const uint4*)(pw + k0); rw1 = *(const uint4*)(pw + k0 + 8);
        }
#pragma unroll
        for (int ks = 0; ks < 2; ++ks) {
            short8 a0 = *(const short8*)&As[wm + fr][ks * 32 + fq * 8];
            short8 a1 = *(const short8*)&As[wm + 16 + fr][ks * 32 + fq * 8];
            short8 b0 = *(const short8*)&Ws[wn + fr][ks * 32 + fq * 8];
            short8 b1 = *(const short8*)&Ws[wn + 16 + fr][ks * 32 + fq * 8];
            acc[0][0] = __builtin_amdgcn_mfma_f32_16x16x32_bf16(a0, b0, acc[0][0], 0, 0, 0);
            acc[0][1] = __builtin_amdgcn_mfma_f32_16x16x32_bf16(a0, b1, acc[0][1], 0, 0, 0);
            acc[1][0] = __builtin_amdgcn_mfma_f32_16x16x32_bf16(a1, b0, acc[1][0], 0, 0, 0);
            acc[1][1] = __builtin_amdgcn_mfma_f32_16x16x32_bf16(a1, b1, acc[1][1], 0, 0, 0);
        }
        if (!more) break;
        __syncthreads();
    }
#pragma unroll
    for (int i = 0; i < 2; ++i) {
#pragma unroll
        for (int r = 0; r < 4; ++r) {
            int row = m0 + wm + i * 16 + fq * 4 + r;
            size_t ro = (size_t)row * N;
#pragma unroll
            for (int j = 0; j < 2; ++j) {
                int col = n0 + wn + j * 16 + fr;
                float c = acc[i][j][r];
                if (bias) c += bias[col];
                if (act == 1) c = gelu(c);
                if (res) c += res[ro + col];
                stc(&C[ro + col], c);
            }
        }
    }
}

// ---------- fused adapter 1: xc += 0.7*(gelu(xfn@dw^T+db)@uw^T+ub) + xfn ----------
// one block per 16 rows; thread (r=t>>4, c=t&15)
__global__ __launch_bounds__(256) void k_adapter1(const float* __restrict__ xfn, const float* __restrict__ dw,
                                                  const float* __restrict__ db, const float* __restrict__ uw,
                                                  const float* __restrict__ ub, float* __restrict__ xc) {
    __shared__ float S[16][400];
    __shared__ float Tl[16][16];
    int t = threadIdx.x;
    int r0 = blockIdx.x * 16;
    for (int i = t * 4; i < 16 * 384; i += 1024) {
        int rr = i / 384, cc = i - rr * 384;
        *(float4*)&S[rr][cc] = *(const float4*)(xfn + (size_t)(r0 + rr) * DD + cc);
    }
    __syncthreads();
    int r = t >> 4, c = t & 15;
    float acc = db[c];
    const float* wp = dw + c * 384;
    for (int k = 0; k < 384; k += 4) {
        float4 sv = *(const float4*)&S[r][k];
        float4 wvv = *(const float4*)(wp + k);
        acc += sv.x * wvv.x + sv.y * wvv.y + sv.z * wvv.z + sv.w * wvv.w;
    }
    Tl[r][c] = gelu(acc);
    __syncthreads();
    float tr[16];
#pragma unroll
    for (int j = 0; j < 4; ++j) *(float4*)&tr[j * 4] = *(const float4*)&Tl[r][j * 4];
    size_t rowoff = (size_t)(r0 + r) * DD;
#pragma unroll 4
    for (int j = 0; j < 24; ++j) {
        int d = c + j * 16;
        float a = ub[d];
        const float4* up4 = (const float4*)(uw + d * 16);
        float4 u0 = up4[0], u1 = up4[1], u2 = up4[2], u3 = up4[3];
        a += tr[0] * u0.x + tr[1] * u0.y + tr[2] * u0.z + tr[3] * u0.w
           + tr[4] * u1.x + tr[5] * u1.y + tr[6] * u1.z + tr[7] * u1.w
           + tr[8] * u2.x + tr[9] * u2.y + tr[10] * u2.z + tr[11] * u2.w
           + tr[12] * u3.x + tr[13] * u3.y + tr[14] * u3.z + tr[15] * u3.w;
        xc[rowoff + d] += 0.7f * a + S[r][d];
    }
}

// ---------- fused final adapter: out = gelu(src@dw^T+db)@uw^T+ub + src, 8256 out rows ----------
__global__ __launch_bounds__(256) void k_adapter2(const float* __restrict__ xc, const float* __restrict__ xp,
                                                  const float* __restrict__ dw, const float* __restrict__ db,
                                                  const float* __restrict__ uw, const float* __restrict__ ub,
                                                  float* __restrict__ outx) {
    __shared__ float S[16][400];
    __shared__ float Tl[16][16];
    int t = threadIdx.x;
    int r0 = blockIdx.x * 16;
    for (int i = t * 4; i < 16 * 384; i += 1024) {
        int rr = i / 384, cc = i - rr * 384;
        int gidx = r0 + rr;
        int b = gidx / 129, no = gidx - b * 129;
        const float* src = (no == 0) ? (xc + (size_t)(b * NT) * DD)
                                     : (xp + (size_t)(b * 128 + no - 1) * DD);
        *(float4*)&S[rr][cc] = *(const float4*)(src + cc);
    }
    __syncthreads();
    int r = t >> 4, c = t & 15;
    float acc = db[c];
    const float* wp = dw + c * 384;
    for (int k = 0; k < 384; k += 4) {
        float4 sv = *(const float4*)&S[r][k];
        float4 wvv = *(const float4*)(wp + k);
        acc += sv.x * wvv.x + sv.y * wvv.y + sv.z * wvv.z + sv.w * wvv.w;
    }
    Tl[r][c] = gelu(acc);
    __syncthreads();
    float tr[16];
#pragma unroll
    for (int j = 0; j < 4; ++j) *(float4*)&tr[j * 4] = *(const float4*)&Tl[r][j * 4];
    size_t rowoff = (size_t)(r0 + r) * DD;
#pragma unroll 4
    for (int j = 0; j < 24; ++j) {
        int d = c + j * 16;
        float a = ub[d];
        const float4* up4 = (const float4*)(uw + d * 16);
        float4 u0 = up4[0], u1 = up4[1], u2 = up4[2], u3 = up4[3];
        a += tr[0] * u0.x + tr[1] * u0.y + tr[2] * u0.z + tr[3] * u0.w
           + tr[4] * u1.x + tr[5] * u1.y + tr[6] * u1.z + tr[7] * u1.w
           + tr[8] * u2.x + tr[9] * u2.y + tr[10] * u2.z + tr[11] * u2.w
           + tr[12] * u3.x + tr[13] * u3.y + tr[14] * u3.z + tr[15] * u3.w;
        outx[rowoff + d] = a + S[r][d];
    }
}

// ---------- stage-1 attention (MFMA): one block per (b,h) ----------
__global__ __launch_bounds__(256) void k_attn1(const bf16* __restrict__ qkv, bf16* __restrict__ o_out,
                                               float* __restrict__ attn_out) {
    int bh = blockIdx.x;
    int b = bh / HH, h = bh % HH;
    __shared__ unsigned short Kl[144][72];
    __shared__ unsigned short Vt[64][160];
    __shared__ unsigned short Pl[4][16][160];
    int t = threadIdx.x;
    int lane = t & 63, wv = t >> 6;
    int fr = lane & 15, fq = lane >> 4;
    const unsigned short* q16 = (const unsigned short*)qkv;
    size_t base = (size_t)b * NT * 1152;

    uint4 z4 = make_uint4(0, 0, 0, 0);
    for (int i = t * 8; i < 64 * 160; i += 2048) *(uint4*)(&Vt[0][0] + i) = z4;
    for (int i = t * 8; i < 4 * 16 * 160; i += 2048) *(uint4*)(&Pl[0][0][0] + i) = z4;
    for (int i = t; i < 144 * 8; i += 256) {
        int row = i >> 3, ch = (i & 7) * 8;
        uint4 v = z4;
        if (row < NT) v = *(const uint4*)(q16 + base + row * 1152 + 384 + h * 64 + ch);
        *(uint4*)&Kl[row][ch] = v;
    }
    for (int i = t; i < NT * 16; i += 256) {
        int m = i >> 4, dq = (i & 15) * 4;
        ushort4 v = *(const ushort4*)(q16 + base + m * 1152 + 768 + h * 64 + dq);
        Vt[dq + 0][m] = v.x; Vt[dq + 1][m] = v.y;
        Vt[dq + 2][m] = v.z; Vt[dq + 3][m] = v.w;
    }
    __syncthreads();

    for (int nt = wv; nt < 9; nt += 4) {
        int n0 = nt * 16;
        int arow = n0 + fr; if (arow > NT - 1) arow = NT - 1;
        const unsigned short* qp = q16 + base + (size_t)arow * 1152 + h * 64 + fq * 8;
        short8 a0 = *(const short8*)qp;
        short8 a1 = *(const short8*)(qp + 32);
        f32x4 s[9] = {};
#pragma unroll
        for (int mt = 0; mt < 9; ++mt) {
            short8 b0 = *(const short8*)&Kl[mt * 16 + fr][fq * 8];
            short8 b1 = *(const short8*)&Kl[mt * 16 + fr][32 + fq * 8];
            s[mt] = __builtin_amdgcn_mfma_f32_16x16x32_bf16(a0, b0, s[mt], 0, 0, 0);
            s[mt] = __builtin_amdgcn_mfma_f32_16x16x32_bf16(a1, b1, s[mt], 0, 0, 0);
        }
#pragma unroll
        for (int r = 0; r < 4; ++r) {
            float e[9];
            float mx = -1e30f;
#pragma unroll
            for (int mt = 0; mt < 9; ++mt) {
                int col = mt * 16 + fr;
                float v = (col < NT) ? s[mt][r] * SCALE : -1e30f;
                e[mt] = v;
                mx = fmaxf(mx, v);
            }
#pragma unroll
            for (int off = 1; off < 16; off <<= 1) mx = fmaxf(mx, __shfl_xor(mx, off, 64));
            float sm = 0.f;
#pragma unroll
            for (int mt = 0; mt < 9; ++mt) { e[mt] = __expf(e[mt] - mx); sm += e[mt]; }
#pragma unroll
            for (int off = 1; off < 16; off <<= 1) sm += __shfl_xor(sm, off, 64);
            float inv = 1.0f / sm;
            int n = n0 + fq * 4 + r;
            bool nv = n < NT;
            size_t ab = ((size_t)(b * HH + h) * NT + n) * NT;
#pragma unroll
            for (int mt = 0; mt < 9; ++mt) {
                float p = e[mt] * inv;
                int col = mt * 16 + fr;
                if (nv && col < NT) attn_out[ab + col] = p;
                Pl[wv][fq * 4 + r][col] = f2bu(p);
            }
        }
        __syncthreads();
        f32x4 oac[4] = {};
#pragma unroll
        for (int ks = 0; ks < 5; ++ks) {
            short8 ap = *(const short8*)&Pl[wv][fr][ks * 32 + fq * 8];
#pragma unroll
            for (int dt = 0; dt < 4; ++dt) {
                short8 bv = *(const short8*)&Vt[dt * 16 + fr][ks * 32 + fq * 8];
                oac[dt] = __builtin_amdgcn_mfma_f32_16x16x32_bf16(ap, bv, oac[dt], 0, 0, 0);
            }
        }
#pragma unroll
        for (int dt = 0; dt < 4; ++dt)
#pragma unroll
            for (int r = 0; r < 4; ++r) {
                int n = n0 + fq * 4 + r;
                if (n < NT)
                    o_out[((size_t)(b * NT + n)) * DD + h * 64 + dt * 16 + fr] = f2b(oac[dt][r]);
            }
    }
}

// ---------- stage-2 per-group attention (MFMA): one wave per group ----------
__global__ __launch_bounds__(64) void k_attn2(const bf16* __restrict__ qkv, const int* __restrict__ idx,
                                              bf16* __restrict__ o1) {
    int g = blockIdx.x;
    __shared__ unsigned short Vt2[64][40];
    __shared__ unsigned short P2[16][40];
    __shared__ int ridx[16];
    int t = threadIdx.x;
    int fr = t & 15, fq = t >> 4;
    const unsigned short* q16 = (const unsigned short*)qkv;
    if (t < 16) ridx[t] = idx[g * 16 + t];
    uint4 z4 = make_uint4(0, 0, 0, 0);
    for (int i = t * 8; i < 64 * 40; i += 512) *(uint4*)(&Vt2[0][0] + i) = z4;
    for (int i = t * 8; i < 16 * 40; i += 512) *(uint4*)(&P2[0][0] + i) = z4;
    __syncthreads();
    size_t qb = (size_t)ridx[fr] * 1152;
    for (int h = 0; h < HH; ++h) {
        for (int i = t; i < 256; i += 64) {
            int m = i >> 4, dq = (i & 15) * 4;
            ushort4 v = *(const ushort4*)(q16 + (size_t)ridx[m] * 1152 + 768 + h * 64 + dq);
            Vt2[dq + 0][m] = v.x; Vt2[dq + 1][m] = v.y;
            Vt2[dq + 2][m] = v.z; Vt2[dq + 3][m] = v.w;
        }
        __syncthreads();
        const unsigned short* qp = q16 + qb + h * 64 + fq * 8;
        const unsigned short* kp = q16 + qb + 384 + h * 64 + fq * 8;
        short8 a0 = *(const short8*)qp;
        short8 a1 = *(const short8*)(qp + 32);
        short8 b0 = *(const short8*)kp;
        short8 b1 = *(const short8*)(kp + 32);
        f32x4 s = {};
        s = __builtin_amdgcn_mfma_f32_16x16x32_bf16(a0, b0, s, 0, 0, 0);
        s = __builtin_amdgcn_mfma_f32_16x16x32_bf16(a1, b1, s, 0, 0, 0);
#pragma unroll
        for (int r = 0; r < 4; ++r) {
            float v = s[r] * SCALE;
            float mx = v;
#pragma unroll
            for (int off = 1; off < 16; off <<= 1) mx = fmaxf(mx, __shfl_xor(mx, off, 64));
            float e = __expf(v - mx), sm = e;
#pragma unroll
            for (int off = 1; off < 16; off <<= 1) sm += __shfl_xor(sm, off, 64);
            P2[fq * 4 + r][fr] = f2bu(e / sm);
        }
        __syncthreads();
        short8 ap = *(const short8*)&P2[fr][fq * 8];
        f32x4 oac[4] = {};
#pragma unroll
        for (int dt = 0; dt < 4; ++dt) {
            short8 bv = *(const short8*)&Vt2[dt * 16 + fr][fq * 8];
            oac[dt] = __builtin_amdgcn_mfma_f32_16x16x32_bf16(ap, bv, oac[dt], 0, 0, 0);
        }
#pragma unroll
        for (int dt = 0; dt < 4; ++dt)
#pragma unroll
            for (int r = 0; r < 4; ++r)
                o1[((size_t)(g * 16 + fq * 4 + r)) * DD + h * 64 + dt * 16 + fr] = f2b(oac[dt][r]);
        __syncthreads();
    }
}

// ---------- group residual + max + BN + GELU + centers -> vis ----------
__global__ __launch_bounds__(128) void k_groupmax(const bf16* __restrict__ att, const float* __restrict__ xc,
                                                  const int* __restrict__ idx, const int* __restrict__ cidx,
                                                  const float* __restrict__ bg, const float* __restrict__ bb,
                                                  const float* __restrict__ bmean, const float* __restrict__ bvar,
                                                  float* __restrict__ vis) {
    int g = blockIdx.x, t = threadIdx.x;
    __shared__ int rows[16];
    __shared__ int crow;
    if (t < 16) { int r = idx[g * 16 + t]; rows[t] = (r / GG) * NT + 1 + (r % GG); }
    if (t == 16) { int r = cidx[g]; crow = (r / GG) * NT + 1 + (r % GG); }
    __syncthreads();
    for (int d = t; d < DD; d += 128) {
        float m = -INFINITY;
#pragma unroll
        for (int j = 0; j < 16; ++j) {
            float v = b2f(att[((size_t)(g * 16 + j)) * DD + d]) + xc[(size_t)rows[j] * DD + d];
            m = fmaxf(m, v);
        }
        float bn = (m - bmean[d]) * rsqrtf(bvar[d] + 1e-5f) * bg[d] + bb[d];
        bn = gelu(bn);
        vis[(size_t)g * DD + d] = bn + 0.3f * xc[(size_t)crow * DD + d];
    }
}

// ---------- propagate ----------
__global__ __launch_bounds__(128) void k_propagate(const float* __restrict__ c1, const float* __restrict__ c2,
                                                   const float* __restrict__ xc, const float* __restrict__ vis,
                                                   float* __restrict__ xp) {
    int blk = blockIdx.x;
    int b = blk >> 7, i = blk & 127;
    int t = threadIdx.x;
    __shared__ float wl[32];
    __shared__ float wsum;
    if (t < 32) {
        float dx = c1[(b * 128 + i) * 3 + 0] - c2[(b * 32 + t) * 3 + 0];
        float dy = c1[(b * 128 + i) * 3 + 1] - c2[(b * 32 + t) * 3 + 1];
        float dz = c1[(b * 128 + i) * 3 + 2] - c2[(b * 32 + t) * 3 + 2];
        wl[t] = 1.0f / (dx * dx + dy * dy + dz * dz + 1e-8f);
    }
    __syncthreads();
    if (t == 0) {
        float s = 0.f;
        for (int j = 0; j < 32; ++j) s += wl[j];
        wsum = s;
    }
    __syncthreads();
    float sc = 0.3f / wsum;
    for (int d = t; d < DD; d += 128) {
        float acc = 0.f;
#pragma unroll 8
        for (int j = 0; j < 32; ++j) acc += wl[j] * vis[((size_t)(b * 32 + j)) * DD + d];
        xp[((size_t)(b * 128 + i)) * DD + d] = xc[((size_t)(b * NT + 11 + i)) * DD + d] + sc * acc;
    }
}

extern "C" void kernel_launch(void* const* d_in, const int* in_sizes, int n_in,
                              void* d_out, int out_size, void* d_ws, size_t ws_size,
                              hipStream_t stream) {
    const float* x_in    = (const float*)d_in[0];
    const float* center1 = (const float*)d_in[2];
    const float* center2 = (const float*)d_in[3];
    const int*   idx     = (const int*)d_in[5];
    const int*   cidx    = (const int*)d_in[6];
    const float* ln1_g   = (const float*)d_in[9];
    const float* ln1_b   = (const float*)d_in[10];
    const float* ln2_g   = (const float*)d_in[11];
    const float* ln2_b   = (const float*)d_in[12];
    const float* qkv_w   = (const float*)d_in[13];
    const float* proj_w  = (const float*)d_in[14];
    const float* proj_b  = (const float*)d_in[15];
    const float* fc1_w   = (const float*)d_in[16];
    const float* fc1_b   = (const float*)d_in[17];
    const float* fc2_w   = (const float*)d_in[18];
    const float* fc2_b   = (const float*)d_in[19];
    const float* ad_dw   = (const float*)d_in[20];
    const float* ad_db   = (const float*)d_in[21];
    const float* ad_uw   = (const float*)d_in[22];
    const float* ad_ub   = (const float*)d_in[23];
    const float* ad1_dw  = (const float*)d_in[24];
    const float* ad1_db  = (const float*)d_in[25];
    const float* ad1_uw  = (const float*)d_in[26];
    const float* ad1_ub  = (const float*)d_in[27];
    const float* prompt  = (const float*)d_in[28];
    const float* bn_g    = (const float*)d_in[29];
    const float* bn_b    = (const float*)d_in[30];
    const float* bn_mean = (const float*)d_in[31];
    const float* bn_var  = (const float*)d_in[32];
    const float* qkv1_w  = (const float*)d_in[33];
    const float* proj1_w = (const float*)d_in[34];
    const float* proj1_b = (const float*)d_in[35];
    const float* ln3_g   = (const float*)d_in[36];
    const float* ln3_b   = (const float*)d_in[37];

    char* wsb = (char*)d_ws;
    float* XC   = (float*)(wsb + XC_OFF);
    float* VIS  = (float*)(wsb + VIS_OFF);
    bf16*  XNB  = (bf16*)(wsb + XNB_OFF);
    float* XFN  = (float*)(wsb + XFN_OFF);
    bf16*  BIG1 = (bf16*)(wsb + BIG1_OFF);
    bf16*  BIG2 = (bf16*)(wsb + BIG2_OFF);
    bf16*  ATT  = (bf16*)(wsb + ATT_OFF);
    bf16*  WB   = (bf16*)(wsb + WB_OFF);

    float* out_x    = (float*)d_out;
    float* out_attn = out_x + OUT_X;

    // --- weights -> bf16 ---
    k_wconv<<<(WB_TOTAL / 4 + 255) / 256, 256, 0, stream>>>(qkv_w, proj_w, fc1_w, fc2_w, qkv1_w, proj1_w, WB);

    // --- stage 1 ---
    k_ln1<<<M1, 128, 0, stream>>>(x_in, prompt, ln1_g, ln1_b, XC, XNB);
    mf_gemm<<<dim3(18, 139), 256, 0, stream>>>(XNB, WB + WB_QKV, (const float*)nullptr, (const float*)nullptr, BIG1, M1, 1152, 384, 0);
    k_attn1<<<BB * HH, 256, 0, stream>>>(BIG1, XNB, out_attn);
    mf_gemm<<<dim3(6, 139), 256, 0, stream>>>(XNB, WB + WB_PROJ, proj_b, XC, XC, M1, 384, 384, 0);
    k_layernorm<<<M1, 128, 0, stream>>>(XC, XNB, ln2_g, ln2_b, 0);
    mf_gemm<<<dim3(24, 139), 256, 0, stream>>>(XNB, WB + WB_FC1, fc1_b, (const float*)nullptr, BIG2, M1, 1536, 384, 1);
    mf_gemm<<<dim3(6, 139), 256, 0, stream>>>(BIG2, WB + WB_FC2, fc2_b, (const float*)nullptr, XFN, M1, 384, 1536, 0);
    k_adapter1<<<M1 / 16, 256, 0, stream>>>(XFN, ad_dw, ad_db, ad_uw, ad_ub, XC);

    // --- stage 2 (group attention on 8832 unique rows) ---
    k_layernorm<<<MG, 128, 0, stream>>>(XC, XNB, ln3_g, ln3_b, 1);
    mf_gemm<<<dim3(18, 138), 256, 0, stream>>>(XNB, WB + WB_QKV1, (const float*)nullptr, (const float*)nullptr, BIG1, MG, 1152, 384, 0);
    k_attn2<<<NGRP, 64, 0, stream>>>(BIG1, idx, BIG2);
    mf_gemm<<<dim3(6, 512), 256, 0, stream>>>(BIG2, WB + WB_PROJ1, proj1_b, (const float*)nullptr, ATT, NGRP * 16, 384, 384, 0);
    k_groupmax<<<NGRP, 128, 0, stream>>>(ATT, XC, idx, cidx, bn_g, bn_b, bn_mean, bn_var, VIS);
    k_propagate<<<BB * 128, 128, 0, stream>>>(center1, center2, XC, VIS, XFN);

    // --- fused final adapter + slice -> out ---
    k_adapter2<<<(BB * 129) / 16, 256, 0, stream>>>(XC, XFN, ad1_dw, ad1_db, ad1_uw, ad1_ub, out_x);
}